// Round 1
// baseline (784.946 us; speedup 1.0000x reference)
//
#include <hip/hip_runtime.h>

#define HH 192
#define WW 256
#define NPIX (HH*WW)   // 49152

__device__ __forceinline__ float lrelu(float v) { return v > 0.0f ? v : 0.01f * v; }

// ---------------- zero the histogram ----------------
__global__ void k_zero(int* __restrict__ count) {
    if (threadIdx.x < 32) count[threadIdx.x] = 0;
}

// ---------------- stage 1a: x = lrelu(Wcl1@a), r = lrelu(Wr1@a), mask branch ----------------
// block = 256 thr (4 waves), 64 pixels; wave w computes rows w*72..w*72+71 of
// W_all = [Wcl1(0..127); Wr1(128..255); Wm1(256..287)]
__global__ __launch_bounds__(256, 1) void k1a(
    const float* __restrict__ X,
    const float* __restrict__ Wcl1, const float* __restrict__ bcl1,
    const float* __restrict__ Wr1,  const float* __restrict__ br1,
    const float* __restrict__ Wm1,  const float* __restrict__ bm1,
    const float* __restrict__ Wm2,  const float* __restrict__ bm2,
    const float* __restrict__ Wm3,  const float* __restrict__ bm3,
    float* __restrict__ x_t, float* __restrict__ r_t,
    float* __restrict__ out)
{
    // A-tile: [c][p] pitch 65 (128x64);  reused as T: [p][row] pitch 129 (64x128)
    __shared__ float S[8320];
    const int tid  = threadIdx.x;
    const int q0   = blockIdx.x * 64;
    const int lane = tid & 63;
    const int wv   = __builtin_amdgcn_readfirstlane(tid >> 6);

    // stage input tile (coalesced: per wave, fixed c, p = lane)
    #pragma unroll
    for (int i = 0; i < 32; ++i) {
        int idx = i * 256 + tid;
        int c = idx >> 6, p = idx & 63;
        S[c * 65 + p] = X[c * NPIX + q0 + p];
    }
    __syncthreads();

    const int r0 = wv * 72;
    float res[72];

    #pragma unroll
    for (int g = 0; g < 9; ++g) {
        int ob = r0 + g * 8;                 // uniform; groups never straddle 128/256 boundaries
        const float* Wp; const float* bp;
        if (ob < 128)      { Wp = Wcl1 + ob * 128;         bp = bcl1 + ob; }
        else if (ob < 256) { Wp = Wr1 + (ob - 128) * 128;  bp = br1 + (ob - 128); }
        else               { Wp = Wm1 + (ob - 256) * 128;  bp = bm1 + (ob - 256); }
        float acc[8];
        #pragma unroll
        for (int oi = 0; oi < 8; ++oi) acc[oi] = bp[oi];
        #pragma unroll 8
        for (int c = 0; c < 128; ++c) {
            float a = S[c * 65 + lane];
            #pragma unroll
            for (int oi = 0; oi < 8; ++oi)
                acc[oi] = fmaf(Wp[oi * 128 + c], a, acc[oi]);
        }
        #pragma unroll
        for (int oi = 0; oi < 8; ++oi) res[g * 8 + oi] = lrelu(acc[oi]);
    }

    // mask branch: wave 3 holds m1 = rows 256..287 in res[40..71]
    if (wv == 3) {
        float m2v[16];
        #pragma unroll
        for (int j = 0; j < 16; ++j) {
            float s = bm2[j];
            #pragma unroll
            for (int k = 0; k < 32; ++k) s = fmaf(Wm2[j * 32 + k], res[40 + k], s);
            m2v[j] = lrelu(s);
        }
        float s3 = bm3[0];
        #pragma unroll
        for (int k = 0; k < 16; ++k) s3 = fmaf(Wm3[k], m2v[k], s3);
        out[NPIX + q0 + lane] = lrelu(s3);
    }

    // ---- transpose-stage x channels, write x_t rows (row n' = w*192 + h) ----
    __syncthreads();                          // A-tile dead
    #pragma unroll
    for (int i = 0; i < 72; ++i) {
        int row = r0 + i;
        if (row < 128) S[lane * 129 + row] = res[i];   // uniform condition
    }
    __syncthreads();
    #pragma unroll
    for (int i = 0; i < 32; ++i) {
        int idx = i * 256 + tid;
        int p = idx >> 7, c = idx & 127;
        int q = q0 + p;
        int np_ = (q & 255) * 192 + (q >> 8);          // w*H + h
        x_t[np_ * 128 + c] = S[p * 129 + c];
    }
    __syncthreads();
    // ---- same for r channels (rows 128..255) ----
    #pragma unroll
    for (int i = 0; i < 72; ++i) {
        int row = r0 + i - 128;
        if (row >= 0 && row < 128) S[lane * 129 + row] = res[i];
    }
    __syncthreads();
    #pragma unroll
    for (int i = 0; i < 32; ++i) {
        int idx = i * 256 + tid;
        int p = idx >> 7, c = idx & 127;
        int q = q0 + p;
        int np_ = (q & 255) * 192 + (q >> 8);
        r_t[np_ * 128 + c] = S[p * 129 + c];
    }
}

// ---------------- stage 1b: x2 = lrelu(Wcl21@x); cl1 = Wcl31@x2; argmax -> inds1 + histogram ----------------
__global__ __launch_bounds__(256, 1) void k1b(
    const float* __restrict__ x_t,
    const float* __restrict__ Wcl21, const float* __restrict__ bcl21,
    const float* __restrict__ Wcl31, const float* __restrict__ bcl31,
    int* __restrict__ inds1, int* __restrict__ count)
{
    __shared__ float S[8320];      // x tile [c][p] pitch 65; then reused for x2 tile
    __shared__ float redv[256];
    __shared__ int   redi[256];
    const int tid  = threadIdx.x;
    const int n0   = blockIdx.x * 64;
    const int lane = tid & 63;
    const int wv   = __builtin_amdgcn_readfirstlane(tid >> 6);

    #pragma unroll
    for (int i = 0; i < 32; ++i) {
        int idx = i * 256 + tid;
        int p = idx >> 7, c = idx & 127;
        S[c * 65 + p] = x_t[(n0 + p) * 128 + c];
    }
    __syncthreads();

    // x2 channels 32*wv .. +31, kept in registers
    float x2loc[32];
    #pragma unroll
    for (int g = 0; g < 4; ++g) {
        int ob = 32 * wv + g * 8;
        float acc[8];
        #pragma unroll
        for (int oi = 0; oi < 8; ++oi) acc[oi] = bcl21[ob + oi];
        #pragma unroll 8
        for (int c = 0; c < 128; ++c) {
            float a = S[c * 65 + lane];
            #pragma unroll
            for (int oi = 0; oi < 8; ++oi)
                acc[oi] = fmaf(Wcl21[(ob + oi) * 128 + c], a, acc[oi]);
        }
        #pragma unroll
        for (int oi = 0; oi < 8; ++oi) x2loc[g * 8 + oi] = lrelu(acc[oi]);
    }
    __syncthreads();               // all waves done reading x tile
    #pragma unroll
    for (int j = 0; j < 32; ++j)
        S[(32 * wv + j) * 65 + lane] = x2loc[j];
    __syncthreads();

    // cl1 channels 8*wv..+7 (no lrelu), per-lane argmax over own 8
    {
        int ob = 8 * wv;
        float acc[8];
        #pragma unroll
        for (int oi = 0; oi < 8; ++oi) acc[oi] = bcl31[ob + oi];
        #pragma unroll 8
        for (int c = 0; c < 128; ++c) {
            float a = S[c * 65 + lane];
            #pragma unroll
            for (int oi = 0; oi < 8; ++oi)
                acc[oi] = fmaf(Wcl31[(ob + oi) * 128 + c], a, acc[oi]);
        }
        float bv = acc[0]; int bi = ob;
        #pragma unroll
        for (int oi = 1; oi < 8; ++oi)
            if (acc[oi] > bv) { bv = acc[oi]; bi = ob + oi; }   // strict > keeps first
        redv[wv * 64 + lane] = bv;
        redi[wv * 64 + lane] = bi;
    }
    __syncthreads();
    if (tid < 64) {
        float bv = redv[tid]; int bi = redi[tid];
        #pragma unroll
        for (int w = 1; w < 4; ++w) {        // ascending wave = ascending channel: first-index tiebreak
            float v = redv[w * 64 + tid];
            if (v > bv) { bv = v; bi = redi[w * 64 + tid]; }
        }
        int n = n0 + tid;
        int wq = n / 192, hq = n - wq * 192;     // row n = pixel (h=hq, w=wq)
        inds1[hq * 256 + wq] = bi;               // q-order scatter
        // ballot histogram (wave 0, all 64 lanes active)
        for (int k = 0; k < 32; ++k) {
            unsigned long long m = __ballot(bi == k);
            if (tid == 0 && m) atomicAdd(&count[k], __popcll(m));
        }
    }
}

// ---------------- prefix sum over 32 classes ----------------
__global__ void k_scan(const int* __restrict__ count, int* __restrict__ offs, int* __restrict__ cursor) {
    if (threadIdx.x == 0) {
        int s = 0;
        for (int k = 0; k < 32; ++k) { offs[k] = s; cursor[k * 16] = s; s += count[k]; }
    }
}

// ---------------- bucket pixels by inds1 ----------------
__global__ void k_scatter(const int* __restrict__ inds1, int* __restrict__ cursor, int* __restrict__ order) {
    int n = blockIdx.x * 256 + threadIdx.x;
    int i1 = inds1[n];
    int pos = atomicAdd(&cursor[i1 * 16], 1);   // counters padded to separate lines
    order[pos] = n;
}

// ---------------- stage 2: cond_mul chains, class-uniform weights ----------------
__global__ __launch_bounds__(256, 1) void k2(
    const float* __restrict__ x_t, const float* __restrict__ r_t,
    const float* __restrict__ Wcl22, const float* __restrict__ bcl22,
    const float* __restrict__ Wcl32, const float* __restrict__ bcl32,
    const float* __restrict__ Wr2,  const float* __restrict__ br2,
    const float* __restrict__ Wr3,  const float* __restrict__ br3,
    const int* __restrict__ count, const int* __restrict__ offs,
    const int* __restrict__ order,
    float* __restrict__ out)
{
    const int cls = blockIdx.y;
    const int cnt = count[cls];
    const int local = blockIdx.x * 256 + threadIdx.x;
    if (local >= cnt) return;
    const int n = order[offs[cls] + local];

    const float* Wa = Wcl22 + cls * (128 * 32);
    const float* ba = bcl22 + cls * 32;
    const float* Wb = Wcl32 + cls * (32 * 32);
    const float* bb = bcl32 + cls * 32;
    const int sup = cls >> 2;                 // isuper = i1>>2 exactly (range proof)
    const float* Wc = Wr2 + sup * (128 * 32);
    const float* bc = br2 + sup * 32;

    float xr[128];
    const float4* xp = (const float4*)(x_t + n * 128);
    #pragma unroll
    for (int i = 0; i < 32; ++i) {
        float4 v = xp[i];
        xr[4*i] = v.x; xr[4*i+1] = v.y; xr[4*i+2] = v.z; xr[4*i+3] = v.w;
    }

    float h[32];
    #pragma unroll
    for (int j = 0; j < 32; ++j) h[j] = ba[j];
    #pragma unroll 4
    for (int c = 0; c < 128; ++c) {
        float xv = xr[c];
        #pragma unroll
        for (int j = 0; j < 32; ++j) h[j] = fmaf(xv, Wa[c * 32 + j], h[j]);
    }
    #pragma unroll
    for (int j = 0; j < 32; ++j) h[j] = lrelu(h[j]);

    float g[32];
    #pragma unroll
    for (int j = 0; j < 32; ++j) g[j] = bb[j];
    #pragma unroll 4
    for (int c = 0; c < 32; ++c) {
        float hv = h[c];
        #pragma unroll
        for (int j = 0; j < 32; ++j) g[j] = fmaf(hv, Wb[c * 32 + j], g[j]);
    }
    float bv = g[0]; int bi = 0;
    #pragma unroll
    for (int j = 1; j < 32; ++j)
        if (g[j] > bv) { bv = g[j]; bi = j; }
    const int ind = cls * 32 + bi;            // clip is a no-op (0..1023)

    float rr[128];
    const float4* rp = (const float4*)(r_t + n * 128);
    #pragma unroll
    for (int i = 0; i < 32; ++i) {
        float4 v = rp[i];
        rr[4*i] = v.x; rr[4*i+1] = v.y; rr[4*i+2] = v.z; rr[4*i+3] = v.w;
    }
    float r2[32];
    #pragma unroll
    for (int j = 0; j < 32; ++j) r2[j] = bc[j];
    #pragma unroll 4
    for (int c = 0; c < 128; ++c) {
        float rv = rr[c];
        #pragma unroll
        for (int j = 0; j < 32; ++j) r2[j] = fmaf(rv, Wc[c * 32 + j], r2[j]);
    }
    float reg = br3[ind];
    const float* w3 = Wr3 + ind * 32;
    #pragma unroll
    for (int j = 0; j < 32; ++j) reg = fmaf(lrelu(r2[j]), w3[j], reg);

    out[n] = ((float)ind + reg) * (1.0f / 1024.0f);
}

extern "C" void kernel_launch(void* const* d_in, const int* in_sizes, int n_in,
                              void* d_out, int out_size, void* d_ws, size_t ws_size,
                              hipStream_t stream)
{
    const float* X     = (const float*)d_in[0];
    const float* Wm1   = (const float*)d_in[1];
    const float* bm1   = (const float*)d_in[2];
    const float* Wm2   = (const float*)d_in[3];
    const float* bm2   = (const float*)d_in[4];
    const float* Wm3   = (const float*)d_in[5];
    const float* bm3   = (const float*)d_in[6];
    const float* Wcl1  = (const float*)d_in[7];
    const float* bcl1  = (const float*)d_in[8];
    const float* Wcl21 = (const float*)d_in[9];
    const float* bcl21 = (const float*)d_in[10];
    const float* Wcl31 = (const float*)d_in[11];
    const float* bcl31 = (const float*)d_in[12];
    const float* Wcl22 = (const float*)d_in[13];
    const float* bcl22 = (const float*)d_in[14];
    const float* Wcl32 = (const float*)d_in[15];
    const float* bcl32 = (const float*)d_in[16];
    const float* Wr1   = (const float*)d_in[17];
    const float* br1   = (const float*)d_in[18];
    const float* Wr2   = (const float*)d_in[19];
    const float* br2   = (const float*)d_in[20];
    const float* Wr3   = (const float*)d_in[21];
    const float* br3   = (const float*)d_in[22];
    float* out = (float*)d_out;

    // workspace: x_t (25.2MB) + r_t (25.2MB) + inds1 + order + counters  (~48.5 MiB)
    float* x_t  = (float*)d_ws;
    float* r_t  = x_t + (size_t)NPIX * 128;
    int* inds1  = (int*)(r_t + (size_t)NPIX * 128);
    int* order  = inds1 + NPIX;
    int* count  = order + NPIX;
    int* offs   = count + 32;
    int* cursor = offs + 32;    // 32*16 padded ints

    k_zero<<<1, 64, 0, stream>>>(count);
    k1a<<<NPIX / 64, 256, 0, stream>>>(X, Wcl1, bcl1, Wr1, br1, Wm1, bm1,
                                       Wm2, bm2, Wm3, bm3, x_t, r_t, out);
    k1b<<<NPIX / 64, 256, 0, stream>>>(x_t, Wcl21, bcl21, Wcl31, bcl31, inds1, count);
    k_scan<<<1, 64, 0, stream>>>(count, offs, cursor);
    k_scatter<<<NPIX / 256, 256, 0, stream>>>(inds1, cursor, order);
    k2<<<dim3(192, 32), 256, 0, stream>>>(x_t, r_t, Wcl22, bcl22, Wcl32, bcl32,
                                          Wr2, br2, Wr3, br3, count, offs, order, out);
}

// Round 2
// 281.123 us; speedup vs baseline: 2.7922x; 2.7922x over previous
//
#include <hip/hip_runtime.h>

#define HH 192
#define WW 256
#define NPIX (HH*WW)   // 49152
#define NSEG (NPIX/64) // 768

__device__ __forceinline__ float lrelu(float v) { return v > 0.0f ? v : 0.01f * v; }

// ============================================================================
// k_gemm1: OUT_t = lrelu(W @ X) for W = Wcl1 (y=0) or Wr1 (y=1), stored
// transposed-to-row-major: out_t[np*128 + row], np = w*192 + h.
// Tile: 128 px x 128 rows, K=128 in chunks of 16. 256 thr, 8x8 micro-tile.
// Hot loop: 4 ds_read_b128 + 64 FMA per k-step (VALU-bound by construction).
// ============================================================================
__global__ __launch_bounds__(256, 2) void k_gemm1(
    const float* __restrict__ X,
    const float* __restrict__ W0, const float* __restrict__ b0,
    const float* __restrict__ W1, const float* __restrict__ b1,
    float* __restrict__ x_t, float* __restrict__ r_t)
{
    __shared__ float As[16][132];
    __shared__ float Ws[16][132];
    const int tid = threadIdx.x;
    const int q0  = blockIdx.x * 128;
    const float* __restrict__ W    = (blockIdx.y == 0) ? W0 : W1;
    const float* __restrict__ bias = (blockIdx.y == 0) ? b0 : b1;
    float* __restrict__ outp       = (blockIdx.y == 0) ? x_t : r_t;

    const int tc = tid & 15;      // px group: {tc*4+i, 64+tc*4+i}
    const int tr = tid >> 4;      // row group: {tr*4+j, 64+tr*4+j}

    float acc[8][8];
    #pragma unroll
    for (int i = 0; i < 8; ++i)
        #pragma unroll
        for (int j = 0; j < 8; ++j)
            acc[i][j] = bias[(j >> 2) * 64 + tr * 4 + (j & 3)];

    for (int k0 = 0; k0 < 128; k0 += 16) {
        // stage A: As[kk][px] = X[(k0+kk)*NPIX + q0 + px]  (channel-major: no transpose)
        #pragma unroll
        for (int p = 0; p < 2; ++p) {
            int lin = p * 1024 + tid * 4;
            int kk = lin >> 7, px = lin & 127;
            float4 v = *(const float4*)(X + (k0 + kk) * NPIX + q0 + px);
            *(float4*)(&As[kk][px]) = v;
        }
        // stage W transposed: Ws[kk][row] = W[row*128 + k0 + kk]
        #pragma unroll
        for (int p = 0; p < 2; ++p) {
            int lin = p * 1024 + tid * 4;
            int row = lin >> 4, kc = lin & 15;
            float4 v = *(const float4*)(W + row * 128 + k0 + kc);
            Ws[kc + 0][row] = v.x; Ws[kc + 1][row] = v.y;
            Ws[kc + 2][row] = v.z; Ws[kc + 3][row] = v.w;
        }
        __syncthreads();
        #pragma unroll
        for (int kk = 0; kk < 16; ++kk) {
            float4 a0 = *(const float4*)(&As[kk][tc * 4]);
            float4 a1 = *(const float4*)(&As[kk][64 + tc * 4]);
            float4 w0 = *(const float4*)(&Ws[kk][tr * 4]);
            float4 w1 = *(const float4*)(&Ws[kk][64 + tr * 4]);
            float av[8] = {a0.x,a0.y,a0.z,a0.w,a1.x,a1.y,a1.z,a1.w};
            float wv[8] = {w0.x,w0.y,w0.z,w0.w,w1.x,w1.y,w1.z,w1.w};
            #pragma unroll
            for (int i = 0; i < 8; ++i)
                #pragma unroll
                for (int j = 0; j < 8; ++j)
                    acc[i][j] = fmaf(av[i], wv[j], acc[i][j]);
        }
        __syncthreads();
    }

    // epilogue: lrelu + transposed store (rows tr*4..+3 and 64+tr*4..+3 per px)
    #pragma unroll
    for (int i = 0; i < 8; ++i) {
        int px = (i >> 2) * 64 + tc * 4 + (i & 3);
        int q  = q0 + px;
        int np = (q & 255) * 192 + (q >> 8);
        float* op = outp + (size_t)np * 128;
        #pragma unroll
        for (int jg = 0; jg < 2; ++jg) {
            float4 o;
            o.x = lrelu(acc[i][jg*4+0]); o.y = lrelu(acc[i][jg*4+1]);
            o.z = lrelu(acc[i][jg*4+2]); o.w = lrelu(acc[i][jg*4+3]);
            *(float4*)(op + jg * 64 + tr * 4) = o;
        }
    }
}

// ============================================================================
// k_mask: full mask branch. m1 = lrelu(Wm1@X) (tiled GEMM, 128px x 32 rows),
// then per-pixel m2/m3 from LDS. Writes out[NPIX + q].
// ============================================================================
__global__ __launch_bounds__(256, 2) void k_mask(
    const float* __restrict__ X,
    const float* __restrict__ Wm1, const float* __restrict__ bm1,
    const float* __restrict__ Wm2, const float* __restrict__ bm2,
    const float* __restrict__ Wm3, const float* __restrict__ bm3,
    float* __restrict__ out)
{
    __shared__ float As[16][132];
    __shared__ float Ws[16][36];
    __shared__ float m1buf[128][33];
    const int tid = threadIdx.x;
    const int q0  = blockIdx.x * 128;
    const int tc = tid & 31;   // px {tc*4..+3}
    const int tr = tid >> 5;   // rows {tr*4..+3}

    float acc[4][4];
    #pragma unroll
    for (int i = 0; i < 4; ++i)
        #pragma unroll
        for (int j = 0; j < 4; ++j)
            acc[i][j] = bm1[tr * 4 + j];

    for (int k0 = 0; k0 < 128; k0 += 16) {
        #pragma unroll
        for (int p = 0; p < 2; ++p) {
            int lin = p * 1024 + tid * 4;
            int kk = lin >> 7, px = lin & 127;
            float4 v = *(const float4*)(X + (k0 + kk) * NPIX + q0 + px);
            *(float4*)(&As[kk][px]) = v;
        }
        if (tid < 128) {
            int row = tid >> 2, kc = (tid & 3) * 4;
            float4 v = *(const float4*)(Wm1 + row * 128 + k0 + kc);
            Ws[kc + 0][row] = v.x; Ws[kc + 1][row] = v.y;
            Ws[kc + 2][row] = v.z; Ws[kc + 3][row] = v.w;
        }
        __syncthreads();
        #pragma unroll
        for (int kk = 0; kk < 16; ++kk) {
            float4 a = *(const float4*)(&As[kk][tc * 4]);
            float4 w = *(const float4*)(&Ws[kk][tr * 4]);
            float av[4] = {a.x,a.y,a.z,a.w};
            float wv[4] = {w.x,w.y,w.z,w.w};
            #pragma unroll
            for (int i = 0; i < 4; ++i)
                #pragma unroll
                for (int j = 0; j < 4; ++j)
                    acc[i][j] = fmaf(av[i], wv[j], acc[i][j]);
        }
        __syncthreads();
    }
    #pragma unroll
    for (int i = 0; i < 4; ++i)
        #pragma unroll
        for (int j = 0; j < 4; ++j)
            m1buf[tc * 4 + i][tr * 4 + j] = lrelu(acc[i][j]);
    __syncthreads();
    if (tid < 128) {
        float m3 = bm3[0];
        #pragma unroll 2
        for (int j = 0; j < 16; ++j) {
            float s = bm2[j];
            #pragma unroll
            for (int k = 0; k < 32; ++k)
                s = fmaf(Wm2[j * 32 + k], m1buf[tid][k], s);
            m3 = fmaf(Wm3[j], lrelu(s), m3);
        }
        out[NPIX + q0 + tid] = lrelu(m3);
    }
}

// ============================================================================
// k1b: x2 = lrelu(Wcl21@x), cl1 = Wcl31@x2 + argmax -> inds1_q (q-order).
// 128 px/block; x2 computed in two 64-row halves through LDS; cl1 accumulated
// across halves. All weights staged in LDS; hot loops pure ds_read + FMA.
// ============================================================================
__global__ __launch_bounds__(256, 2) void k1b(
    const float* __restrict__ x_t,
    const float* __restrict__ Wcl21, const float* __restrict__ bcl21,
    const float* __restrict__ Wcl31, const float* __restrict__ bcl31,
    int* __restrict__ inds1_q)
{
    __shared__ float smem[12672];                 // 50688 B
    float (*As)[132]     = (float(*)[132])smem;            // [16][132]
    float (*Ws)[132]     = (float(*)[132])(smem + 2112);   // [16][132] (64 cols used)
    float (*W31)[132]    = (float(*)[132])smem;            // [32][132] overlays As+Ws
    float (*x2t)[132]    = (float(*)[132])(smem + 4224);   // [64][132]
    float (*cl1buf)[33]  = (float(*)[33]) (smem + 4224);   // [128][33] overlays x2t

    const int tid = threadIdx.x;
    const int n0  = blockIdx.x * 128;
    const int tcA = tid & 15, trA = tid >> 4;   // phase A: 8px x 4rows
    const int tcB = tid & 31, trB = tid >> 5;   // phase B: 4px x 4cls

    float accB[4][4];
    #pragma unroll
    for (int i = 0; i < 4; ++i)
        #pragma unroll
        for (int j = 0; j < 4; ++j)
            accB[i][j] = bcl31[trB * 4 + j];

    for (int h = 0; h < 2; ++h) {
        // ---- phase A: x2 rows h*64 .. h*64+63 ----
        float acc2[2][4][4];
        #pragma unroll
        for (int gi = 0; gi < 2; ++gi)
            #pragma unroll
            for (int i = 0; i < 4; ++i)
                #pragma unroll
                for (int j = 0; j < 4; ++j)
                    acc2[gi][i][j] = bcl21[h * 64 + trA * 4 + j];

        for (int k0 = 0; k0 < 128; k0 += 16) {
            // stage A transposed from x_t: As[kk][px] = x_t[(n0+px)*128 + k0+kk]
            #pragma unroll
            for (int p = 0; p < 2; ++p) {
                int lin = p * 1024 + tid * 4;
                int px = lin >> 4, kc = lin & 15;
                float4 v = *(const float4*)(x_t + (size_t)(n0 + px) * 128 + k0 + kc);
                As[kc + 0][px] = v.x; As[kc + 1][px] = v.y;
                As[kc + 2][px] = v.z; As[kc + 3][px] = v.w;
            }
            // stage Wcl21 rows h*64..+63 transposed: Ws[kk][r] = Wcl21[(h*64+r)*128 + k0+kk]
            {
                int r = tid >> 2, kc = (tid & 3) * 4;
                float4 v = *(const float4*)(Wcl21 + (h * 64 + r) * 128 + k0 + kc);
                Ws[kc + 0][r] = v.x; Ws[kc + 1][r] = v.y;
                Ws[kc + 2][r] = v.z; Ws[kc + 3][r] = v.w;
            }
            __syncthreads();
            #pragma unroll
            for (int kk = 0; kk < 16; ++kk) {
                float4 a0 = *(const float4*)(&As[kk][tcA * 4]);
                float4 a1 = *(const float4*)(&As[kk][64 + tcA * 4]);
                float4 w  = *(const float4*)(&Ws[kk][trA * 4]);
                float av0[4] = {a0.x,a0.y,a0.z,a0.w};
                float av1[4] = {a1.x,a1.y,a1.z,a1.w};
                float wv[4]  = {w.x,w.y,w.z,w.w};
                #pragma unroll
                for (int i = 0; i < 4; ++i)
                    #pragma unroll
                    for (int j = 0; j < 4; ++j) {
                        acc2[0][i][j] = fmaf(av0[i], wv[j], acc2[0][i][j]);
                        acc2[1][i][j] = fmaf(av1[i], wv[j], acc2[1][i][j]);
                    }
            }
            __syncthreads();
        }
        // write x2 (lrelu) to x2t[row][px]
        #pragma unroll
        for (int j = 0; j < 4; ++j) {
            int row = trA * 4 + j;
            #pragma unroll
            for (int gi = 0; gi < 2; ++gi) {
                float4 o;
                o.x = lrelu(acc2[gi][0][j]); o.y = lrelu(acc2[gi][1][j]);
                o.z = lrelu(acc2[gi][2][j]); o.w = lrelu(acc2[gi][3][j]);
                *(float4*)(&x2t[row][gi * 64 + tcA * 4]) = o;
            }
        }
        __syncthreads();
        // ---- phase B: stage Wcl31 (row-major, padded pitch), accumulate cl1 ----
        #pragma unroll
        for (int p = 0; p < 4; ++p) {
            int lin = p * 1024 + tid * 4;
            int row = lin >> 7, kc = lin & 127;
            *(float4*)(&W31[row][kc]) = *(const float4*)(Wcl31 + row * 128 + kc);
        }
        __syncthreads();
        for (int k = 0; k < 64; ++k) {
            float4 a = *(const float4*)(&x2t[k][tcB * 4]);
            float av[4] = {a.x,a.y,a.z,a.w};
            float wv[4];
            #pragma unroll
            for (int j = 0; j < 4; ++j) wv[j] = W31[trB * 4 + j][h * 64 + k];
            #pragma unroll
            for (int i = 0; i < 4; ++i)
                #pragma unroll
                for (int j = 0; j < 4; ++j)
                    accB[i][j] = fmaf(av[i], wv[j], accB[i][j]);
        }
        __syncthreads();
    }

    // cl1 -> LDS, per-pixel argmax
    #pragma unroll
    for (int i = 0; i < 4; ++i)
        #pragma unroll
        for (int j = 0; j < 4; ++j)
            cl1buf[tcB * 4 + i][trB * 4 + j] = accB[i][j];
    __syncthreads();
    if (tid < 128) {
        float bv = cl1buf[tid][0]; int bi = 0;
        #pragma unroll
        for (int c = 1; c < 32; ++c) {
            float v = cl1buf[tid][c];
            if (v > bv) { bv = v; bi = c; }
        }
        int n = n0 + tid;
        int w = n / 192, hh = n - w * 192;
        inds1_q[hh * 256 + w] = bi;          // q-order (reference pairing quirk)
    }
}

// ============================================================================
// bucketing chain: per-64-seg ballot histograms -> per-class scan -> class
// bases -> deterministic rank scatter. Zero atomics.
// key(n) = inds1_q[n]  (coalesced read; matches reference x_l[n] <-> inds1[n])
// ============================================================================
__global__ void k_hist(const int* __restrict__ inds1_q, int* __restrict__ bh) {
    int tid = threadIdx.x;
    int n = blockIdx.x * 256 + tid;
    int key = inds1_q[n];
    int lane = tid & 63;
    int cnt = 0;
    for (int k = 0; k < 32; ++k) {
        unsigned long long m = __ballot(key == k);
        if (lane == k) cnt = __popcll(m);
    }
    if (lane < 32) bh[(n >> 6) * 32 + lane] = cnt;
}

__global__ void k_scanA(const int* __restrict__ bh, int* __restrict__ ebb,
                        int* __restrict__ total) {
    __shared__ int s[256];
    const int k = blockIdx.x, t = threadIdx.x;
    int v0 = bh[(t * 3 + 0) * 32 + k];
    int v1 = bh[(t * 3 + 1) * 32 + k];
    int v2 = bh[(t * 3 + 2) * 32 + k];
    int sum = v0 + v1 + v2;
    s[t] = sum; __syncthreads();
    for (int d = 1; d < 256; d <<= 1) {
        int x = (t >= d) ? s[t - d] : 0;
        __syncthreads();
        s[t] += x;
        __syncthreads();
    }
    int ex = s[t] - sum;
    ebb[(t * 3 + 0) * 32 + k] = ex;
    ebb[(t * 3 + 1) * 32 + k] = ex + v0;
    ebb[(t * 3 + 2) * 32 + k] = ex + v0 + v1;
    if (t == 255) total[k] = s[255];
}

__global__ void k_scanB(const int* __restrict__ total, int* __restrict__ classbase) {
    if (threadIdx.x == 0) {
        int s = 0;
        for (int k = 0; k < 32; ++k) { classbase[k] = s; s += total[k]; }
    }
}

__global__ void k_scatter2(const int* __restrict__ inds1_q,
                           const int* __restrict__ ebb,
                           const int* __restrict__ classbase,
                           int* __restrict__ order) {
    int tid = threadIdx.x;
    int n = blockIdx.x * 256 + tid;
    int key = inds1_q[n];
    int lane = tid & 63;
    unsigned long long peers = 0;
    for (int k = 0; k < 32; ++k) {
        unsigned long long m = __ballot(key == k);
        if (key == k) peers = m;
    }
    int rank = __popcll(peers & ((1ull << lane) - 1ull));
    int pos = classbase[key] + ebb[(n >> 6) * 32 + key] + rank;
    order[pos] = n;
}

// ============================================================================
// k2: cond_mul chains with block-uniform class. Streams x/r rows in float4
// chunks (no 128-float register buffers).
// ============================================================================
__global__ __launch_bounds__(256, 2) void k2(
    const float* __restrict__ x_t, const float* __restrict__ r_t,
    const float* __restrict__ Wcl22, const float* __restrict__ bcl22,
    const float* __restrict__ Wcl32, const float* __restrict__ bcl32,
    const float* __restrict__ Wr2,  const float* __restrict__ br2,
    const float* __restrict__ Wr3,  const float* __restrict__ br3,
    const int* __restrict__ total, const int* __restrict__ classbase,
    const int* __restrict__ order,
    float* __restrict__ out)
{
    const int cls = blockIdx.y;
    const int cnt = total[cls];
    const int local = blockIdx.x * 256 + threadIdx.x;
    if (local >= cnt) return;
    const int n = order[classbase[cls] + local];

    const float* __restrict__ Wa = Wcl22 + cls * 4096;
    const float* __restrict__ ba = bcl22 + cls * 32;
    const float* __restrict__ Wb = Wcl32 + cls * 1024;
    const float* __restrict__ bb = bcl32 + cls * 32;
    const int sup = cls >> 2;
    const float* __restrict__ Wc = Wr2 + sup * 4096;
    const float* __restrict__ bc = br2 + sup * 32;

    float h[32];
    #pragma unroll
    for (int j = 0; j < 32; ++j) h[j] = ba[j];
    const float4* xp = (const float4*)(x_t + (size_t)n * 128);
    #pragma unroll 2
    for (int c4 = 0; c4 < 32; ++c4) {
        float4 v = xp[c4];
        const float* wr = Wa + c4 * 128;
        #pragma unroll
        for (int j = 0; j < 32; ++j) h[j] = fmaf(v.x, wr[j], h[j]);
        #pragma unroll
        for (int j = 0; j < 32; ++j) h[j] = fmaf(v.y, wr[32 + j], h[j]);
        #pragma unroll
        for (int j = 0; j < 32; ++j) h[j] = fmaf(v.z, wr[64 + j], h[j]);
        #pragma unroll
        for (int j = 0; j < 32; ++j) h[j] = fmaf(v.w, wr[96 + j], h[j]);
    }
    #pragma unroll
    for (int j = 0; j < 32; ++j) h[j] = lrelu(h[j]);

    float g[32];
    #pragma unroll
    for (int j = 0; j < 32; ++j) g[j] = bb[j];
    #pragma unroll 4
    for (int c = 0; c < 32; ++c) {
        float hv = h[c];
        #pragma unroll
        for (int j = 0; j < 32; ++j) g[j] = fmaf(hv, Wb[c * 32 + j], g[j]);
    }
    float bv = g[0]; int bi = 0;
    #pragma unroll
    for (int j = 1; j < 32; ++j)
        if (g[j] > bv) { bv = g[j]; bi = j; }
    const int ind = cls * 32 + bi;

    float r2[32];
    #pragma unroll
    for (int j = 0; j < 32; ++j) r2[j] = bc[j];
    const float4* rp = (const float4*)(r_t + (size_t)n * 128);
    #pragma unroll 2
    for (int c4 = 0; c4 < 32; ++c4) {
        float4 v = rp[c4];
        const float* wr = Wc + c4 * 128;
        #pragma unroll
        for (int j = 0; j < 32; ++j) r2[j] = fmaf(v.x, wr[j], r2[j]);
        #pragma unroll
        for (int j = 0; j < 32; ++j) r2[j] = fmaf(v.y, wr[32 + j], r2[j]);
        #pragma unroll
        for (int j = 0; j < 32; ++j) r2[j] = fmaf(v.z, wr[64 + j], r2[j]);
        #pragma unroll
        for (int j = 0; j < 32; ++j) r2[j] = fmaf(v.w, wr[96 + j], r2[j]);
    }
    float reg = br3[ind];
    const float* __restrict__ w3 = Wr3 + ind * 32;
    #pragma unroll
    for (int j = 0; j < 32; ++j) reg = fmaf(lrelu(r2[j]), w3[j], reg);

    out[n] = ((float)ind + reg) * (1.0f / 1024.0f);
}

extern "C" void kernel_launch(void* const* d_in, const int* in_sizes, int n_in,
                              void* d_out, int out_size, void* d_ws, size_t ws_size,
                              hipStream_t stream)
{
    const float* X     = (const float*)d_in[0];
    const float* Wm1   = (const float*)d_in[1];
    const float* bm1   = (const float*)d_in[2];
    const float* Wm2   = (const float*)d_in[3];
    const float* bm2   = (const float*)d_in[4];
    const float* Wm3   = (const float*)d_in[5];
    const float* bm3   = (const float*)d_in[6];
    const float* Wcl1  = (const float*)d_in[7];
    const float* bcl1  = (const float*)d_in[8];
    const float* Wcl21 = (const float*)d_in[9];
    const float* bcl21 = (const float*)d_in[10];
    const float* Wcl31 = (const float*)d_in[11];
    const float* bcl31 = (const float*)d_in[12];
    const float* Wcl22 = (const float*)d_in[13];
    const float* bcl22 = (const float*)d_in[14];
    const float* Wcl32 = (const float*)d_in[15];
    const float* bcl32 = (const float*)d_in[16];
    const float* Wr1   = (const float*)d_in[17];
    const float* br1   = (const float*)d_in[18];
    const float* Wr2   = (const float*)d_in[19];
    const float* br2   = (const float*)d_in[20];
    const float* Wr3   = (const float*)d_in[21];
    const float* br3   = (const float*)d_in[22];
    float* out = (float*)d_out;

    float* x_t    = (float*)d_ws;
    float* r_t    = x_t + (size_t)NPIX * 128;
    int* inds1_q  = (int*)(r_t + (size_t)NPIX * 128);
    int* order    = inds1_q + NPIX;
    int* bh       = order + NPIX;          // [768][32]
    int* ebb      = bh + NSEG * 32;        // [768][32]
    int* total    = ebb + NSEG * 32;       // [32]
    int* classbase= total + 32;            // [32]

    k_gemm1<<<dim3(NPIX / 128, 2), 256, 0, stream>>>(X, Wcl1, bcl1, Wr1, br1, x_t, r_t);
    k_mask<<<NPIX / 128, 256, 0, stream>>>(X, Wm1, bm1, Wm2, bm2, Wm3, bm3, out);
    k1b<<<NPIX / 128, 256, 0, stream>>>(x_t, Wcl21, bcl21, Wcl31, bcl31, inds1_q);
    k_hist<<<NPIX / 256, 256, 0, stream>>>(inds1_q, bh);
    k_scanA<<<32, 256, 0, stream>>>(bh, ebb, total);
    k_scanB<<<1, 64, 0, stream>>>(total, classbase);
    k_scatter2<<<NPIX / 256, 256, 0, stream>>>(inds1_q, ebb, classbase, order);
    k2<<<dim3(192, 32), 256, 0, stream>>>(x_t, r_t, Wcl22, bcl22, Wcl32, bcl32,
                                          Wr2, br2, Wr3, br3, total, classbase, order, out);
}

// Round 3
// 280.834 us; speedup vs baseline: 2.7951x; 1.0010x over previous
//
#include <hip/hip_runtime.h>

#define HH 192
#define WW 256
#define NPIX (HH*WW)   // 49152
#define NSEG (NPIX/64) // 768

__device__ __forceinline__ float lrelu(float v) { return v > 0.0f ? v : 0.01f * v; }

// ============================================================================
// k_gemm1: OUT_t = lrelu(W @ X) for W = Wcl1 (y=0) or Wr1 (y=1), stored
// transposed-to-row-major: out_t[np*128 + row], np = w*192 + h.
// ============================================================================
__global__ __launch_bounds__(256, 2) void k_gemm1(
    const float* __restrict__ X,
    const float* __restrict__ W0, const float* __restrict__ b0,
    const float* __restrict__ W1, const float* __restrict__ b1,
    float* __restrict__ x_t, float* __restrict__ r_t)
{
    __shared__ float As[16][132];
    __shared__ float Ws[16][132];
    const int tid = threadIdx.x;
    const int q0  = blockIdx.x * 128;
    const float* __restrict__ W    = (blockIdx.y == 0) ? W0 : W1;
    const float* __restrict__ bias = (blockIdx.y == 0) ? b0 : b1;
    float* __restrict__ outp       = (blockIdx.y == 0) ? x_t : r_t;

    const int tc = tid & 15;      // px group: {tc*4+i, 64+tc*4+i}
    const int tr = tid >> 4;      // row group: {tr*4+j, 64+tr*4+j}

    float acc[8][8];
    #pragma unroll
    for (int i = 0; i < 8; ++i)
        #pragma unroll
        for (int j = 0; j < 8; ++j)
            acc[i][j] = bias[(j >> 2) * 64 + tr * 4 + (j & 3)];

    for (int k0 = 0; k0 < 128; k0 += 16) {
        #pragma unroll
        for (int p = 0; p < 2; ++p) {
            int lin = p * 1024 + tid * 4;
            int kk = lin >> 7, px = lin & 127;
            float4 v = *(const float4*)(X + (k0 + kk) * NPIX + q0 + px);
            *(float4*)(&As[kk][px]) = v;
        }
        #pragma unroll
        for (int p = 0; p < 2; ++p) {
            int lin = p * 1024 + tid * 4;
            int row = lin >> 4, kc = lin & 15;
            float4 v = *(const float4*)(W + row * 128 + k0 + kc);
            Ws[kc + 0][row] = v.x; Ws[kc + 1][row] = v.y;
            Ws[kc + 2][row] = v.z; Ws[kc + 3][row] = v.w;
        }
        __syncthreads();
        #pragma unroll
        for (int kk = 0; kk < 16; ++kk) {
            float4 a0 = *(const float4*)(&As[kk][tc * 4]);
            float4 a1 = *(const float4*)(&As[kk][64 + tc * 4]);
            float4 w0 = *(const float4*)(&Ws[kk][tr * 4]);
            float4 w1 = *(const float4*)(&Ws[kk][64 + tr * 4]);
            float av[8] = {a0.x,a0.y,a0.z,a0.w,a1.x,a1.y,a1.z,a1.w};
            float wv[8] = {w0.x,w0.y,w0.z,w0.w,w1.x,w1.y,w1.z,w1.w};
            #pragma unroll
            for (int i = 0; i < 8; ++i)
                #pragma unroll
                for (int j = 0; j < 8; ++j)
                    acc[i][j] = fmaf(av[i], wv[j], acc[i][j]);
        }
        __syncthreads();
    }

    #pragma unroll
    for (int i = 0; i < 8; ++i) {
        int px = (i >> 2) * 64 + tc * 4 + (i & 3);
        int q  = q0 + px;
        int np = (q & 255) * 192 + (q >> 8);
        float* op = outp + (size_t)np * 128;
        #pragma unroll
        for (int jg = 0; jg < 2; ++jg) {
            float4 o;
            o.x = lrelu(acc[i][jg*4+0]); o.y = lrelu(acc[i][jg*4+1]);
            o.z = lrelu(acc[i][jg*4+2]); o.w = lrelu(acc[i][jg*4+3]);
            *(float4*)(op + jg * 64 + tr * 4) = o;
        }
    }
}

// ============================================================================
// k_mask: full mask branch.
// ============================================================================
__global__ __launch_bounds__(256, 2) void k_mask(
    const float* __restrict__ X,
    const float* __restrict__ Wm1, const float* __restrict__ bm1,
    const float* __restrict__ Wm2, const float* __restrict__ bm2,
    const float* __restrict__ Wm3, const float* __restrict__ bm3,
    float* __restrict__ out)
{
    __shared__ float As[16][132];
    __shared__ float Ws[16][36];
    __shared__ float m1buf[128][33];
    const int tid = threadIdx.x;
    const int q0  = blockIdx.x * 128;
    const int tc = tid & 31;
    const int tr = tid >> 5;

    float acc[4][4];
    #pragma unroll
    for (int i = 0; i < 4; ++i)
        #pragma unroll
        for (int j = 0; j < 4; ++j)
            acc[i][j] = bm1[tr * 4 + j];

    for (int k0 = 0; k0 < 128; k0 += 16) {
        #pragma unroll
        for (int p = 0; p < 2; ++p) {
            int lin = p * 1024 + tid * 4;
            int kk = lin >> 7, px = lin & 127;
            float4 v = *(const float4*)(X + (k0 + kk) * NPIX + q0 + px);
            *(float4*)(&As[kk][px]) = v;
        }
        if (tid < 128) {
            int row = tid >> 2, kc = (tid & 3) * 4;
            float4 v = *(const float4*)(Wm1 + row * 128 + k0 + kc);
            Ws[kc + 0][row] = v.x; Ws[kc + 1][row] = v.y;
            Ws[kc + 2][row] = v.z; Ws[kc + 3][row] = v.w;
        }
        __syncthreads();
        #pragma unroll
        for (int kk = 0; kk < 16; ++kk) {
            float4 a = *(const float4*)(&As[kk][tc * 4]);
            float4 w = *(const float4*)(&Ws[kk][tr * 4]);
            float av[4] = {a.x,a.y,a.z,a.w};
            float wv[4] = {w.x,w.y,w.z,w.w};
            #pragma unroll
            for (int i = 0; i < 4; ++i)
                #pragma unroll
                for (int j = 0; j < 4; ++j)
                    acc[i][j] = fmaf(av[i], wv[j], acc[i][j]);
        }
        __syncthreads();
    }
    #pragma unroll
    for (int i = 0; i < 4; ++i)
        #pragma unroll
        for (int j = 0; j < 4; ++j)
            m1buf[tc * 4 + i][tr * 4 + j] = lrelu(acc[i][j]);
    __syncthreads();
    if (tid < 128) {
        float m3 = bm3[0];
        #pragma unroll 2
        for (int j = 0; j < 16; ++j) {
            float s = bm2[j];
            #pragma unroll
            for (int k = 0; k < 32; ++k)
                s = fmaf(Wm2[j * 32 + k], m1buf[tid][k], s);
            m3 = fmaf(Wm3[j], lrelu(s), m3);
        }
        out[NPIX + q0 + tid] = lrelu(m3);
    }
}

// ============================================================================
// k1b: x2 = lrelu(Wcl21@x), cl1 = Wcl31@x2 + argmax -> inds1_q (q-order).
// ============================================================================
__global__ __launch_bounds__(256, 2) void k1b(
    const float* __restrict__ x_t,
    const float* __restrict__ Wcl21, const float* __restrict__ bcl21,
    const float* __restrict__ Wcl31, const float* __restrict__ bcl31,
    int* __restrict__ inds1_q)
{
    __shared__ float smem[12672];
    float (*As)[132]     = (float(*)[132])smem;
    float (*Ws)[132]     = (float(*)[132])(smem + 2112);
    float (*W31)[132]    = (float(*)[132])smem;
    float (*x2t)[132]    = (float(*)[132])(smem + 4224);
    float (*cl1buf)[33]  = (float(*)[33]) (smem + 4224);

    const int tid = threadIdx.x;
    const int n0  = blockIdx.x * 128;
    const int tcA = tid & 15, trA = tid >> 4;
    const int tcB = tid & 31, trB = tid >> 5;

    float accB[4][4];
    #pragma unroll
    for (int i = 0; i < 4; ++i)
        #pragma unroll
        for (int j = 0; j < 4; ++j)
            accB[i][j] = bcl31[trB * 4 + j];

    for (int h = 0; h < 2; ++h) {
        float acc2[2][4][4];
        #pragma unroll
        for (int gi = 0; gi < 2; ++gi)
            #pragma unroll
            for (int i = 0; i < 4; ++i)
                #pragma unroll
                for (int j = 0; j < 4; ++j)
                    acc2[gi][i][j] = bcl21[h * 64 + trA * 4 + j];

        for (int k0 = 0; k0 < 128; k0 += 16) {
            #pragma unroll
            for (int p = 0; p < 2; ++p) {
                int lin = p * 1024 + tid * 4;
                int px = lin >> 4, kc = lin & 15;
                float4 v = *(const float4*)(x_t + (size_t)(n0 + px) * 128 + k0 + kc);
                As[kc + 0][px] = v.x; As[kc + 1][px] = v.y;
                As[kc + 2][px] = v.z; As[kc + 3][px] = v.w;
            }
            {
                int r = tid >> 2, kc = (tid & 3) * 4;
                float4 v = *(const float4*)(Wcl21 + (h * 64 + r) * 128 + k0 + kc);
                Ws[kc + 0][r] = v.x; Ws[kc + 1][r] = v.y;
                Ws[kc + 2][r] = v.z; Ws[kc + 3][r] = v.w;
            }
            __syncthreads();
            #pragma unroll
            for (int kk = 0; kk < 16; ++kk) {
                float4 a0 = *(const float4*)(&As[kk][tcA * 4]);
                float4 a1 = *(const float4*)(&As[kk][64 + tcA * 4]);
                float4 w  = *(const float4*)(&Ws[kk][trA * 4]);
                float av0[4] = {a0.x,a0.y,a0.z,a0.w};
                float av1[4] = {a1.x,a1.y,a1.z,a1.w};
                float wv[4]  = {w.x,w.y,w.z,w.w};
                #pragma unroll
                for (int i = 0; i < 4; ++i)
                    #pragma unroll
                    for (int j = 0; j < 4; ++j) {
                        acc2[0][i][j] = fmaf(av0[i], wv[j], acc2[0][i][j]);
                        acc2[1][i][j] = fmaf(av1[i], wv[j], acc2[1][i][j]);
                    }
            }
            __syncthreads();
        }
        #pragma unroll
        for (int j = 0; j < 4; ++j) {
            int row = trA * 4 + j;
            #pragma unroll
            for (int gi = 0; gi < 2; ++gi) {
                float4 o;
                o.x = lrelu(acc2[gi][0][j]); o.y = lrelu(acc2[gi][1][j]);
                o.z = lrelu(acc2[gi][2][j]); o.w = lrelu(acc2[gi][3][j]);
                *(float4*)(&x2t[row][gi * 64 + tcA * 4]) = o;
            }
        }
        __syncthreads();
        #pragma unroll
        for (int p = 0; p < 4; ++p) {
            int lin = p * 1024 + tid * 4;
            int row = lin >> 7, kc = lin & 127;
            *(float4*)(&W31[row][kc]) = *(const float4*)(Wcl31 + row * 128 + kc);
        }
        __syncthreads();
        for (int k = 0; k < 64; ++k) {
            float4 a = *(const float4*)(&x2t[k][tcB * 4]);
            float av[4] = {a.x,a.y,a.z,a.w};
            float wv[4];
            #pragma unroll
            for (int j = 0; j < 4; ++j) wv[j] = W31[trB * 4 + j][h * 64 + k];
            #pragma unroll
            for (int i = 0; i < 4; ++i)
                #pragma unroll
                for (int j = 0; j < 4; ++j)
                    accB[i][j] = fmaf(av[i], wv[j], accB[i][j]);
        }
        __syncthreads();
    }

    #pragma unroll
    for (int i = 0; i < 4; ++i)
        #pragma unroll
        for (int j = 0; j < 4; ++j)
            cl1buf[tcB * 4 + i][trB * 4 + j] = accB[i][j];
    __syncthreads();
    if (tid < 128) {
        float bv = cl1buf[tid][0]; int bi = 0;
        #pragma unroll
        for (int c = 1; c < 32; ++c) {
            float v = cl1buf[tid][c];
            if (v > bv) { bv = v; bi = c; }
        }
        int n = n0 + tid;
        int w = n / 192, hh = n - w * 192;
        inds1_q[hh * 256 + w] = bi;
    }
}

// ============================================================================
// bucketing chain (deterministic, no atomics)
// ============================================================================
__global__ void k_hist(const int* __restrict__ inds1_q, int* __restrict__ bh) {
    int tid = threadIdx.x;
    int n = blockIdx.x * 256 + tid;
    int key = inds1_q[n];
    int lane = tid & 63;
    int cnt = 0;
    for (int k = 0; k < 32; ++k) {
        unsigned long long m = __ballot(key == k);
        if (lane == k) cnt = __popcll(m);
    }
    if (lane < 32) bh[(n >> 6) * 32 + lane] = cnt;
}

__global__ void k_scanA(const int* __restrict__ bh, int* __restrict__ ebb,
                        int* __restrict__ total) {
    __shared__ int s[256];
    const int k = blockIdx.x, t = threadIdx.x;
    int v0 = bh[(t * 3 + 0) * 32 + k];
    int v1 = bh[(t * 3 + 1) * 32 + k];
    int v2 = bh[(t * 3 + 2) * 32 + k];
    int sum = v0 + v1 + v2;
    s[t] = sum; __syncthreads();
    for (int d = 1; d < 256; d <<= 1) {
        int x = (t >= d) ? s[t - d] : 0;
        __syncthreads();
        s[t] += x;
        __syncthreads();
    }
    int ex = s[t] - sum;
    ebb[(t * 3 + 0) * 32 + k] = ex;
    ebb[(t * 3 + 1) * 32 + k] = ex + v0;
    ebb[(t * 3 + 2) * 32 + k] = ex + v0 + v1;
    if (t == 255) total[k] = s[255];
}

// builds classbase + 64-px chunk worklist: chunk = (cls<<20)|startLocal
__global__ void k_scanB(const int* __restrict__ total, int* __restrict__ classbase,
                        int* __restrict__ chunklist, int* __restrict__ meta) {
    if (threadIdx.x == 0) {
        int s = 0, nc = 0;
        for (int k = 0; k < 32; ++k) {
            classbase[k] = s;
            int c = total[k];
            for (int st = 0; st < c; st += 64) chunklist[nc++] = (k << 20) | st;
            s += c;
        }
        meta[0] = nc;
    }
}

__global__ void k_scatter2(const int* __restrict__ inds1_q,
                           const int* __restrict__ ebb,
                           const int* __restrict__ classbase,
                           int* __restrict__ order) {
    int tid = threadIdx.x;
    int n = blockIdx.x * 256 + tid;
    int key = inds1_q[n];
    int lane = tid & 63;
    unsigned long long peers = 0;
    for (int k = 0; k < 32; ++k) {
        unsigned long long m = __ballot(key == k);
        if (key == k) peers = m;
    }
    int rank = __popcll(peers & ((1ull << lane) - 1ull));
    int pos = classbase[key] + ebb[(n >> 6) * 32 + key] + rank;
    order[pos] = n;
}

// ============================================================================
// k2b: class-chunked stage-2. Per 64-px chunk: cooperative coalesced staging
// of gathered x_t/r_t rows into LDS (4 lanes x 16B per row => full 64B lines),
// then broadcast-LDS x scalar-weight FMA. Compact grid-stride over chunklist.
// LDS ~50KB => 3 blocks/CU (12 waves/CU).
// ============================================================================
__global__ __launch_bounds__(256, 3) void k2b(
    const float* __restrict__ x_t, const float* __restrict__ r_t,
    const float* __restrict__ Wcl22, const float* __restrict__ bcl22,
    const float* __restrict__ Wcl32, const float* __restrict__ bcl32,
    const float* __restrict__ Wr2,  const float* __restrict__ br2,
    const float* __restrict__ Wr3,  const float* __restrict__ br3,
    const int* __restrict__ classbase, const int* __restrict__ total,
    const int* __restrict__ order, const int* __restrict__ chunklist,
    const int* __restrict__ meta,
    float* __restrict__ out)
{
    __shared__ float Xs[128][65];   // feature tile, [c][px]: px-consecutive banks
    __shared__ float Hs[32][65];
    __shared__ float Gs[32][65];
    __shared__ int ns[64];
    __shared__ int indbuf[64];

    const int tid  = threadIdx.x;
    const int px   = tid & 63;
    const int grp  = __builtin_amdgcn_readfirstlane(tid >> 6);
    const int row  = tid >> 2;      // staging: 4 threads per row
    const int part = tid & 3;
    const int nchunks = meta[0];

    for (int ci = blockIdx.x; ci < nchunks; ci += gridDim.x) {
        const int packed = chunklist[ci];
        const int cls = __builtin_amdgcn_readfirstlane(packed >> 20);
        const int st  = __builtin_amdgcn_readfirstlane(packed & 0xFFFFF);
        const int npx = min(64, total[cls] - st);
        const int base = classbase[cls] + st;

        if (tid < 64) ns[tid] = order[base + min(tid, npx - 1)];
        __syncthreads();

        // ---- stage X rows ----
        {
            const float* src = x_t + (size_t)ns[row] * 128;
            #pragma unroll
            for (int j = 0; j < 8; ++j) {
                int c = (j * 4 + part) * 4;
                float4 v = *(const float4*)(src + c);
                Xs[c+0][row] = v.x; Xs[c+1][row] = v.y;
                Xs[c+2][row] = v.z; Xs[c+3][row] = v.w;
            }
        }
        __syncthreads();

        // ---- h = lrelu(ba + x @ Wa) : 8 channels per thread ----
        const float* __restrict__ Wa = Wcl22 + cls * 4096 + grp * 8;
        const float* __restrict__ ba = bcl22 + cls * 32 + grp * 8;
        float hv[8];
        #pragma unroll
        for (int oi = 0; oi < 8; ++oi) hv[oi] = ba[oi];
        #pragma unroll 4
        for (int c = 0; c < 128; ++c) {
            float xv = Xs[c][px];
            #pragma unroll
            for (int oi = 0; oi < 8; ++oi)
                hv[oi] = fmaf(xv, Wa[c * 32 + oi], hv[oi]);
        }
        #pragma unroll
        for (int oi = 0; oi < 8; ++oi) Hs[grp * 8 + oi][px] = lrelu(hv[oi]);
        __syncthreads();

        // ---- g = bb + h @ Wb ----
        const float* __restrict__ Wb = Wcl32 + cls * 1024 + grp * 8;
        const float* __restrict__ bb = bcl32 + cls * 32 + grp * 8;
        float gv[8];
        #pragma unroll
        for (int oi = 0; oi < 8; ++oi) gv[oi] = bb[oi];
        #pragma unroll 4
        for (int c = 0; c < 32; ++c) {
            float hvv = Hs[c][px];
            #pragma unroll
            for (int oi = 0; oi < 8; ++oi)
                gv[oi] = fmaf(hvv, Wb[c * 32 + oi], gv[oi]);
        }
        #pragma unroll
        for (int oi = 0; oi < 8; ++oi) Gs[grp * 8 + oi][px] = gv[oi];
        __syncthreads();

        // ---- argmax (wave 0) + stage R rows (all threads) ----
        if (tid < 64) {
            float bv = Gs[0][tid]; int bi = 0;
            #pragma unroll
            for (int c = 1; c < 32; ++c) {
                float v = Gs[c][tid];
                if (v > bv) { bv = v; bi = c; }
            }
            indbuf[tid] = cls * 32 + bi;
        }
        {
            const float* src = r_t + (size_t)ns[row] * 128;
            #pragma unroll
            for (int j = 0; j < 8; ++j) {
                int c = (j * 4 + part) * 4;
                float4 v = *(const float4*)(src + c);
                Xs[c+0][row] = v.x; Xs[c+1][row] = v.y;
                Xs[c+2][row] = v.z; Xs[c+3][row] = v.w;
            }
        }
        __syncthreads();

        // ---- r2 = lrelu(bc + r @ Wc) ----
        const int sup = cls >> 2;
        const float* __restrict__ Wc = Wr2 + sup * 4096 + grp * 8;
        const float* __restrict__ bc = br2 + sup * 32 + grp * 8;
        float rv[8];
        #pragma unroll
        for (int oi = 0; oi < 8; ++oi) rv[oi] = bc[oi];
        #pragma unroll 4
        for (int c = 0; c < 128; ++c) {
            float xv = Xs[c][px];
            #pragma unroll
            for (int oi = 0; oi < 8; ++oi)
                rv[oi] = fmaf(xv, Wc[c * 32 + oi], rv[oi]);
        }
        #pragma unroll
        for (int oi = 0; oi < 8; ++oi) Hs[grp * 8 + oi][px] = lrelu(rv[oi]);
        __syncthreads();

        // ---- final: reg = br3[ind] + r2 @ Wr3[ind] (wave 0, per-px gather) ----
        if (tid < npx) {
            int ind = indbuf[tid];
            const float* __restrict__ w3 = Wr3 + ind * 32;
            float reg = br3[ind];
            #pragma unroll
            for (int c = 0; c < 32; ++c)
                reg = fmaf(Hs[c][tid], w3[c], reg);
            out[ns[tid]] = ((float)ind + reg) * (1.0f / 1024.0f);
        }
        __syncthreads();
    }
}

extern "C" void kernel_launch(void* const* d_in, const int* in_sizes, int n_in,
                              void* d_out, int out_size, void* d_ws, size_t ws_size,
                              hipStream_t stream)
{
    const float* X     = (const float*)d_in[0];
    const float* Wm1   = (const float*)d_in[1];
    const float* bm1   = (const float*)d_in[2];
    const float* Wm2   = (const float*)d_in[3];
    const float* bm2   = (const float*)d_in[4];
    const float* Wm3   = (const float*)d_in[5];
    const float* bm3   = (const float*)d_in[6];
    const float* Wcl1  = (const float*)d_in[7];
    const float* bcl1  = (const float*)d_in[8];
    const float* Wcl21 = (const float*)d_in[9];
    const float* bcl21 = (const float*)d_in[10];
    const float* Wcl31 = (const float*)d_in[11];
    const float* bcl31 = (const float*)d_in[12];
    const float* Wcl22 = (const float*)d_in[13];
    const float* bcl22 = (const float*)d_in[14];
    const float* Wcl32 = (const float*)d_in[15];
    const float* bcl32 = (const float*)d_in[16];
    const float* Wr1   = (const float*)d_in[17];
    const float* br1   = (const float*)d_in[18];
    const float* Wr2   = (const float*)d_in[19];
    const float* br2   = (const float*)d_in[20];
    const float* Wr3   = (const float*)d_in[21];
    const float* br3   = (const float*)d_in[22];
    float* out = (float*)d_out;

    float* x_t     = (float*)d_ws;
    float* r_t     = x_t + (size_t)NPIX * 128;
    int* inds1_q   = (int*)(r_t + (size_t)NPIX * 128);
    int* order     = inds1_q + NPIX;
    int* bh        = order + NPIX;          // [768][32]
    int* ebb       = bh + NSEG * 32;        // [768][32]
    int* total     = ebb + NSEG * 32;       // [32]
    int* classbase = total + 32;            // [32]
    int* chunklist = classbase + 32;        // [1024]
    int* meta      = chunklist + 1024;      // [1]

    k_gemm1<<<dim3(NPIX / 128, 2), 256, 0, stream>>>(X, Wcl1, bcl1, Wr1, br1, x_t, r_t);
    k_mask<<<NPIX / 128, 256, 0, stream>>>(X, Wm1, bm1, Wm2, bm2, Wm3, bm3, out);
    k1b<<<NPIX / 128, 256, 0, stream>>>(x_t, Wcl21, bcl21, Wcl31, bcl31, inds1_q);
    k_hist<<<NPIX / 256, 256, 0, stream>>>(inds1_q, bh);
    k_scanA<<<32, 256, 0, stream>>>(bh, ebb, total);
    k_scanB<<<1, 64, 0, stream>>>(total, classbase, chunklist, meta);
    k_scatter2<<<NPIX / 256, 256, 0, stream>>>(inds1_q, ebb, classbase, order);
    k2b<<<768, 256, 0, stream>>>(x_t, r_t, Wcl22, bcl22, Wcl32, bcl32,
                                 Wr2, br2, Wr3, br3, classbase, total, order,
                                 chunklist, meta, out);
}